// Round 13
// baseline (139.129 us; speedup 1.0000x reference)
//
#include <hip/hip_runtime.h>

// Problem dims (hard-coded in reference)
#define DD   768
#define NN   512
#define MM   512

#define PRE_K 2.88539008177792681472f   // 2*log2(e)

typedef _Float16 h8 __attribute__((ext_vector_type(8)));  // 8 f16 (4 VGPRs)
typedef __attribute__((ext_vector_type(4))) float f32x4;  // MFMA C/D

__device__ __forceinline__ float fexp(float x) { return __builtin_amdgcn_exp2f(x); }
__device__ __forceinline__ float frcp(float x) { return __builtin_amdgcn_rcpf(x); }
// tanh(x) = 1 - 2/(1 + e^{2x}); saturates correctly via exp2->inf/0 + rcp.
// Uses the PRECISE v_exp (cval accuracy multiplies into every sigmoid arg).
__device__ __forceinline__ float fast_tanh(float x) {
  return 1.0f - 2.0f * frcp(fexp(PRE_K * x) + 1.0f);
}

// Schraudolph fast exp2: bitcast(int(p*2^23 + C)). ~±4% rel err on e ->
// <=0.01 abs err on sigmoid; random-sign accumulation over ~230 unsaturated
// d's adds ~0.15 absmax (margin 0.5 vs 2.51). clamp keeps int32 in range
// (p>128 would saturate cvt -> NaN bitcast). med3+fma+cvt = 6 cyc vs 8 for
// v_exp, and moves off the quarter-rate trans pipe (73% of main's issue).
__device__ __forceinline__ float fast_exp2(float p) {
  p = __builtin_fminf(__builtin_fmaxf(p, -126.0f), 120.0f);   // med3
  return __builtin_bit_cast(float, (int)fmaf(p, 8388608.0f, 1064866808.0f));
}

// fp32 -> f16 hi/lo split (pair covers ~21 mantissa bits)
__device__ __forceinline__ void splitf(float x, ushort& h, ushort& l) {
  const _Float16 hh = (_Float16)x;
  const _Float16 ll = (_Float16)(x - (float)hh);
  h = __builtin_bit_cast(unsigned short, hh);
  l = __builtin_bit_cast(unsigned short, ll);
}

// ---- fused prep: convert text/visual/W3 + transpose-convert W1/W2 ----------
__global__ __launch_bounds__(256) void prep_kernel(
    const float* __restrict__ text, const float* __restrict__ visual,
    const float* __restrict__ W1, const float* __restrict__ W2,
    const float* __restrict__ W3,
    ushort* __restrict__ th, ushort* __restrict__ tl,
    ushort* __restrict__ vh, ushort* __restrict__ vl,
    ushort* __restrict__ w3h, ushort* __restrict__ w3l,
    ushort* __restrict__ w1th, ushort* __restrict__ w1tl,
    ushort* __restrict__ w2th, ushort* __restrict__ w2tl)
{
  __shared__ float Lt[32][33];
  const int b = blockIdx.x;
  const int t = threadIdx.x;

  if (b < 1344) {
    const float* src; ushort *dh, *dl; size_t off;
    if (b < 384)      { src = text;   dh = th;  dl = tl;  off = (size_t)b * 1024; }
    else if (b < 768) { src = visual; dh = vh;  dl = vl;  off = (size_t)(b - 384) * 1024; }
    else              { src = W3;     dh = w3h; dl = w3l; off = (size_t)(b - 768) * 1024; }
    const size_t i = off + (size_t)t * 4;
    const float4 v = *(const float4*)&src[i];
    ushort4 h, l;
    splitf(v.x, h.x, l.x); splitf(v.y, h.y, l.y);
    splitf(v.z, h.z, l.z); splitf(v.w, h.w, l.w);
    *(ushort4*)&dh[i] = h;
    *(ushort4*)&dl[i] = l;
  } else {
    const int tt = b - 1344;
    const bool second = tt >= 576;
    const int tile = second ? tt - 576 : tt;
    const float* W = second ? W2 : W1;
    ushort* oh = second ? w2th : w1th;
    ushort* ol = second ? w2tl : w1tl;
    const int k0 = (tile / 24) * 32, j0 = (tile % 24) * 32;
    {
      const int k = t >> 3, j4 = (t & 7) * 4;
      const float4 v = *(const float4*)&W[(size_t)(k0 + k) * DD + j0 + j4];
      Lt[j4 + 0][k] = v.x; Lt[j4 + 1][k] = v.y;
      Lt[j4 + 2][k] = v.z; Lt[j4 + 3][k] = v.w;
    }
    __syncthreads();
    {
      const int j = t >> 3, k4 = (t & 7) * 4;
      ushort4 h, l;
      splitf(Lt[j][k4 + 0], h.x, l.x); splitf(Lt[j][k4 + 1], h.y, l.y);
      splitf(Lt[j][k4 + 2], h.z, l.z); splitf(Lt[j][k4 + 3], h.w, l.w);
      *(ushort4*)&oh[(size_t)(j0 + j) * DD + k0 + k4] = h;
      *(ushort4*)&ol[(size_t)(j0 + j) * DD + k0 + k4] = l;
    }
  }
}

// ---- staged-LDS MFMA GEMM core (proven R8/R9) ------------------------------
// ALO=false drops the a_lo*b_hi term (and a_lo staging entirely): used for the
// kw2t/kw3v GEMMs whose output only feeds the sigmoid argument.
#define BK   32
#define LROW 40   // padded LDS row stride (f16): 2-way banks, 16B-aligned

template <bool ALO>
__device__ __forceinline__ void gemm_core(
    const ushort* __restrict__ Ahg, const ushort* __restrict__ Alg,
    const ushort* __restrict__ Bhg, const ushort* __restrict__ Blg,
    int i0, int j0, int k0, int nsteps, f32x4* acc)
{
  __shared__ ushort As[2][2][64 * LROW];   // [buf][hi/lo][row*LROW+k]
  __shared__ ushort Bs[2][2][64 * LROW];

  const int tid  = threadIdx.x;
  const int row  = tid >> 2;            // 0..63 staging row
  const int ks8  = (tid & 3) * 8;       // 0,8,16,24 (f16)
  const size_t ga = (size_t)(i0 + row) * DD + k0 + ks8;
  const size_t gb = (size_t)(j0 + row) * DD + k0 + ks8;
  const int ldsw = row * LROW + ks8;

  const int lane = tid & 63, wave = tid >> 6;
  const int r15 = lane & 15, quad = lane >> 4;
  const int fa = (wave * 16 + r15) * LROW + quad * 8;   // A frag offset
  const int fb = r15 * LROW + quad * 8;                 // B frag base

  // prefetch step 0
  h8 pah = *(const h8*)(Ahg + ga);
  h8 pal; if (ALO) pal = *(const h8*)(Alg + ga);
  h8 pbh = *(const h8*)(Bhg + gb);
  h8 pbl = *(const h8*)(Blg + gb);

  int p = 0;
  *(h8*)&As[0][0][ldsw] = pah;
  if (ALO) *(h8*)&As[0][1][ldsw] = pal;
  *(h8*)&Bs[0][0][ldsw] = pbh; *(h8*)&Bs[0][1][ldsw] = pbl;
  __syncthreads();

  for (int s = 0; s < nsteps; ++s) {
    const bool more = (s + 1 < nsteps);
    if (more) {  // issue next chunk's globals; MFMA below hides latency
      pah = *(const h8*)(Ahg + ga + (s + 1) * BK);
      if (ALO) pal = *(const h8*)(Alg + ga + (s + 1) * BK);
      pbh = *(const h8*)(Bhg + gb + (s + 1) * BK);
      pbl = *(const h8*)(Blg + gb + (s + 1) * BK);
    }
    const h8 a_h = *(const h8*)&As[p][0][fa];
    h8 a_l; if (ALO) a_l = *(const h8*)&As[p][1][fa];
    h8 b_h[4], b_l[4];
    #pragma unroll
    for (int c = 0; c < 4; ++c) {
      b_h[c] = *(const h8*)&Bs[p][0][fb + c * 16 * LROW];
      b_l[c] = *(const h8*)&Bs[p][1][fb + c * 16 * LROW];
    }
    #pragma unroll
    for (int c = 0; c < 4; ++c)
      acc[c] = __builtin_amdgcn_mfma_f32_16x16x32_f16(a_h, b_h[c], acc[c], 0, 0, 0);
    #pragma unroll
    for (int c = 0; c < 4; ++c)
      acc[c] = __builtin_amdgcn_mfma_f32_16x16x32_f16(a_h, b_l[c], acc[c], 0, 0, 0);
    if (ALO) {
      #pragma unroll
      for (int c = 0; c < 4; ++c)
        acc[c] = __builtin_amdgcn_mfma_f32_16x16x32_f16(a_l, b_h[c], acc[c], 0, 0, 0);
    }
    if (more) {
      const int q = p ^ 1;
      *(h8*)&As[q][0][ldsw] = pah;
      if (ALO) *(h8*)&As[q][1][ldsw] = pal;
      *(h8*)&Bs[q][0][ldsw] = pbh; *(h8*)&Bs[q][1][ldsw] = pbl;
    }
    __syncthreads();
    p ^= 1;
  }
}

// z=0: A=text@W1 -> Ah/Al(f16)  z=1: kw2t=PRE_K*text@W2  z=2: kw3v=PRE_K*visual@W3^T
__global__ __launch_bounds__(256) void mfma1_kernel(
    const ushort* __restrict__ th, const ushort* __restrict__ tl,
    const ushort* __restrict__ vh, const ushort* __restrict__ vl,
    const ushort* __restrict__ w1th, const ushort* __restrict__ w1tl,
    const ushort* __restrict__ w2th, const ushort* __restrict__ w2tl,
    const ushort* __restrict__ w3h, const ushort* __restrict__ w3l,
    ushort* __restrict__ Ah, ushort* __restrict__ Al,
    float* __restrict__ kw2t, float* __restrict__ kw3v)
{
  const int z  = blockIdx.z;
  const int j0 = blockIdx.x * 64;
  const int i0 = blockIdx.y * 64;

  f32x4 acc[4];
  #pragma unroll
  for (int c = 0; c < 4; ++c) acc[c] = (f32x4){0.f, 0.f, 0.f, 0.f};

  if (z == 0)
    gemm_core<true >(th, tl, w1th, w1tl, i0, j0, 0, DD / BK, acc);
  else if (z == 1)
    gemm_core<false>(th, tl, w2th, w2tl, i0, j0, 0, DD / BK, acc);
  else
    gemm_core<false>(vh, vl, w3h,  w3l,  i0, j0, 0, DD / BK, acc);

  const int lane = threadIdx.x & 63, wave = threadIdx.x >> 6;
  const int r15 = lane & 15, quad = lane >> 4;
  // C/D layout: col=lane&15 (B row j), row=quad*4+reg (A row i)
  if (z == 0) {
    #pragma unroll
    for (int c = 0; c < 4; ++c)
      #pragma unroll
      for (int r = 0; r < 4; ++r) {
        const size_t o = (size_t)(i0 + wave * 16 + quad * 4 + r) * DD + j0 + c * 16 + r15;
        splitf(acc[c][r], Ah[o], Al[o]);
      }
  } else {
    float* Out = (z == 1) ? kw2t : kw3v;
    #pragma unroll
    for (int c = 0; c < 4; ++c)
      #pragma unroll
      for (int r = 0; r < 4; ++r)
        Out[(size_t)(i0 + wave * 16 + quad * 4 + r) * DD + j0 + c * 16 + r15] =
            acc[c][r] * PRE_K;
  }
}

// Q[z] = A @ visual^T over K quarter z.  grid (8,8,4) = 256 blocks.
__global__ __launch_bounds__(256) void mfma2_kernel(
    const ushort* __restrict__ Ah, const ushort* __restrict__ Al,
    const ushort* __restrict__ vh, const ushort* __restrict__ vl,
    float* __restrict__ Q)
{
  const int z  = blockIdx.z;
  const int j0 = blockIdx.x * 64;
  const int i0 = blockIdx.y * 64;

  f32x4 acc[4];
  #pragma unroll
  for (int c = 0; c < 4; ++c) acc[c] = (f32x4){0.f, 0.f, 0.f, 0.f};
  gemm_core<true>(Ah, Al, vh, vl, i0, j0, z * (DD / 4), (DD / 4) / BK, acc);

  const int lane = threadIdx.x & 63, wave = threadIdx.x >> 6;
  const int r15 = lane & 15, quad = lane >> 4;
  float* Out = Q + (size_t)z * NN * MM;
  #pragma unroll
  for (int c = 0; c < 4; ++c)
    #pragma unroll
    for (int r = 0; r < 4; ++r)
      Out[(size_t)(i0 + wave * 16 + quad * 4 + r) * MM + j0 + c * 16 + r15] = acc[c][r];
}

// ---- main fused kernel (R11-proven config: d-split x3, 1536 blocks, dbuf) --
// cval = tanh(sum_z Q[z][n,m]);
// Spart[z][n,m] = sum_{d in third z} text[n,d]*rcp(1+exp2(kw2t[n,d]+kw3v[m,d]*cval))
// R12 lesson: z x2 (1024 blocks) REGRESSED (47.9 vs 45.0) — fewer co-resident
// blocks = less inter-block stall hiding. Inner loop now uses fast_exp2
// (issue-count reduction: j-iter 176 -> 160 cyc).
#define DCH    64
#define DRANGE 256
#define MLDW   68

__global__ __launch_bounds__(256) void main_kernel(
    const float* __restrict__ text, const float* __restrict__ kw2t,
    const float* __restrict__ kw3v, const float* __restrict__ Q,
    float* __restrict__ Spart)
{
  __shared__ float sbuf[2][64 * MLDW];   // 2 x 17408 B

  const int tid = threadIdx.x;
  const int nl = tid >> 4;
  const int ml = tid & 15;
  const int n0 = blockIdx.y * 16;
  const int m0 = blockIdx.x * 32;
  const int z  = blockIdx.z;
  const int n  = n0 + nl;
  const int mA = m0 + ml, mB = mA + 16;
  const int dbase = z * DRANGE;

  float cA = 0.f, cB = 0.f;
  #pragma unroll
  for (int zz = 0; zz < 4; ++zz) {
    const float* q = Q + (size_t)zz * NN * MM + (size_t)n * MM;
    cA += q[mA]; cB += q[mB];
  }
  cA = fast_tanh(cA); cB = fast_tanh(cB);   // precise exp here

  float4 aA = {0.f, 0.f, 0.f, 0.f};
  float4 aB = {0.f, 0.f, 0.f, 0.f};

  const int srow = tid >> 4;              // staging row 0..15
  const int sc4  = (tid & 15) << 2;       // staging col 0..60
  const float* gt  = &text[(size_t)(n0 + srow) * DD + dbase + sc4];
  const float* g2  = &kw2t[(size_t)(n0 + srow) * DD + dbase + sc4];
  const float* g3a = &kw3v[(size_t)(m0 + srow) * DD + dbase + sc4];
  const float* g3b = &kw3v[(size_t)(m0 + 16 + srow) * DD + dbase + sc4];
  const int wt  = srow * MLDW + sc4;          // text rows
  const int w2  = (16 + srow) * MLDW + sc4;   // kw2t rows
  const int w3a = (32 + srow) * MLDW + sc4;   // kw3v rows (first 16)
  const int w3b = (48 + srow) * MLDW + sc4;   // kw3v rows (second 16)

  // prologue: stage chunk 0 into buffer 0
  float4 rt  = *(const float4*)gt;
  float4 r2  = *(const float4*)g2;
  float4 r3a = *(const float4*)g3a;
  float4 r3b = *(const float4*)g3b;
  int p = 0;
  *(float4*)&sbuf[0][wt]  = rt;
  *(float4*)&sbuf[0][w2]  = r2;
  *(float4*)&sbuf[0][w3a] = r3a;
  *(float4*)&sbuf[0][w3b] = r3b;
  __syncthreads();

  #pragma unroll
  for (int c = 0; c < DRANGE / DCH; ++c) {
    const bool more = (c + 1 < DRANGE / DCH);
    if (more) {  // prefetch next chunk; compute below hides latency
      rt  = *(const float4*)(gt  + (c + 1) * DCH);
      r2  = *(const float4*)(g2  + (c + 1) * DCH);
      r3a = *(const float4*)(g3a + (c + 1) * DCH);
      r3b = *(const float4*)(g3b + (c + 1) * DCH);
    }
    const float* bp = sbuf[p];
    #pragma unroll 4
    for (int j = 0; j < DCH; j += 4) {
      const float4 tv  = *(const float4*)&bp[nl * MLDW + j];
      const float4 w2v = *(const float4*)&bp[(16 + nl) * MLDW + j];
      const float4 w3A = *(const float4*)&bp[(32 + ml) * MLDW + j];
      const float4 w3B = *(const float4*)&bp[(48 + ml) * MLDW + j];
      aA.x = fmaf(tv.x, frcp(fast_exp2(fmaf(w3A.x, cA, w2v.x)) + 1.0f), aA.x);
      aA.y = fmaf(tv.y, frcp(fast_exp2(fmaf(w3A.y, cA, w2v.y)) + 1.0f), aA.y);
      aA.z = fmaf(tv.z, frcp(fast_exp2(fmaf(w3A.z, cA, w2v.z)) + 1.0f), aA.z);
      aA.w = fmaf(tv.w, frcp(fast_exp2(fmaf(w3A.w, cA, w2v.w)) + 1.0f), aA.w);
      aB.x = fmaf(tv.x, frcp(fast_exp2(fmaf(w3B.x, cB, w2v.x)) + 1.0f), aB.x);
      aB.y = fmaf(tv.y, frcp(fast_exp2(fmaf(w3B.y, cB, w2v.y)) + 1.0f), aB.y);
      aB.z = fmaf(tv.z, frcp(fast_exp2(fmaf(w3B.z, cB, w2v.z)) + 1.0f), aB.z);
      aB.w = fmaf(tv.w, frcp(fast_exp2(fmaf(w3B.w, cB, w2v.w)) + 1.0f), aB.w);
    }
    if (more) {
      const int q = p ^ 1;
      *(float4*)&sbuf[q][wt]  = rt;
      *(float4*)&sbuf[q][w2]  = r2;
      *(float4*)&sbuf[q][w3a] = r3a;
      *(float4*)&sbuf[q][w3b] = r3b;
    }
    __syncthreads();   // single barrier per chunk
    p ^= 1;
  }

  float* Sp = Spart + (size_t)z * NN * MM + (size_t)n * MM;
  Sp[mA] = (aA.x + aA.y) + (aA.z + aA.w);
  Sp[mB] = (aB.x + aB.y) + (aB.z + aB.w);
}

// out[n,m] = T[n] - 2*(S0+S1+S2); T computed in-block (absorbs tsum).
__global__ __launch_bounds__(256) void combine_kernel(
    const float* __restrict__ Spart, const float* __restrict__ text,
    float* __restrict__ out)
{
  __shared__ float red[256];
  __shared__ float Tsh[2];
  const int b = blockIdx.x, t = threadIdx.x;
  const int n0 = b * 2;
  const int half = t >> 7;          // which row this thread reduces
  const int lt = t & 127;

  const float* tr = text + (size_t)(n0 + half) * DD;
  float s = 0.f;
  #pragma unroll
  for (int i = 0; i < DD / 128; ++i) s += tr[lt + i * 128];
  red[t] = s;
  __syncthreads();
  #pragma unroll
  for (int st = 64; st > 0; st >>= 1) {
    if (lt < st) red[t] += red[t + st];
    __syncthreads();
  }
  if (lt == 0) Tsh[half] = red[t];
  __syncthreads();

  const size_t i = (size_t)b * 1024 + (size_t)t * 4;
  const size_t S = (size_t)NN * MM;
  const float Tn = Tsh[half];
  const float4 s0 = *(const float4*)&Spart[i];
  const float4 s1 = *(const float4*)&Spart[S + i];
  const float4 s2 = *(const float4*)&Spart[2 * S + i];
  float4 o;
  o.x = Tn - 2.0f * (s0.x + s1.x + s2.x);
  o.y = Tn - 2.0f * (s0.y + s1.y + s2.y);
  o.z = Tn - 2.0f * (s0.z + s1.z + s2.z);
  o.w = Tn - 2.0f * (s0.w + s1.w + s2.w);
  *(float4*)&out[i] = o;
}

// ---- launcher --------------------------------------------------------------
extern "C" void kernel_launch(void* const* d_in, const int* in_sizes, int n_in,
                              void* d_out, int out_size, void* d_ws, size_t ws_size,
                              hipStream_t stream) {
  const float* text   = (const float*)d_in[0];
  const float* visual = (const float*)d_in[1];
  const float* W1     = (const float*)d_in[2];
  const float* W2     = (const float*)d_in[3];
  const float* W3     = (const float*)d_in[4];
  float* out = (float*)d_out;

  // Workspace byte layout (peak 14.25 MB, proven available):
  //   th/tl/vh/vl : f16 hi/lo of text, visual     (4 x 768 KB)
  //   w1t/w2t h,l : f16 hi/lo of W1^T,W2^T [j][k] (4 x 1.125 MB)
  //   w3 h/l      : f16 hi/lo of W3 [j][k]        (2 x 1.125 MB)
  //   Ah/Al       : f16 hi/lo of A                (2 x 768 KB)
  //   kw2t/kw3v   : fp32                          (2 x 1.5 MB)
  // Overlays (stream-serial; sources dead before overwrite):
  //   Q  (4 MB) -> w1th..w2tl       (dead after mfma1; mfma2 writes Q)
  //   Spart (3 MB) -> w3h+w3l+Ah    (w3 dead after mfma1; Ah read by mfma2
  //                                  which completes before main writes Spart)
  char* base = (char*)d_ws;
  ushort* th   = (ushort*)(base);
  ushort* tl   = (ushort*)(base + 786432);
  ushort* vh   = (ushort*)(base + 1572864);
  ushort* vl   = (ushort*)(base + 2359296);
  ushort* w1th = (ushort*)(base + 3145728);
  ushort* w1tl = (ushort*)(base + 4325376);
  ushort* w2th = (ushort*)(base + 5505024);
  ushort* w2tl = (ushort*)(base + 6684672);
  ushort* w3h  = (ushort*)(base + 7864320);
  ushort* w3l  = (ushort*)(base + 9043968);
  ushort* Ah   = (ushort*)(base + 10223616);
  ushort* Al   = (ushort*)(base + 11010048);
  float*  kw2t = (float*) (base + 11796480);
  float*  kw3v = (float*) (base + 13369344);
  float*  Q     = (float*)(base + 3145728);   // 4 MB over w1t/w2t
  float*  Spart = (float*)(base + 7864320);   // 3 MB over w3 + Ah

  hipLaunchKernelGGL(prep_kernel, dim3(2496), dim3(256), 0, stream,
                     text, visual, W1, W2, W3,
                     th, tl, vh, vl, w3h, w3l, w1th, w1tl, w2th, w2tl);
  hipLaunchKernelGGL(mfma1_kernel, dim3(DD / 64, NN / 64, 3), dim3(256), 0, stream,
                     th, tl, vh, vl, w1th, w1tl, w2th, w2tl, w3h, w3l,
                     Ah, Al, kw2t, kw3v);
  hipLaunchKernelGGL(mfma2_kernel, dim3(MM / 64, NN / 64, 4), dim3(256), 0, stream,
                     Ah, Al, vh, vl, Q);
  hipLaunchKernelGGL(main_kernel, dim3(MM / 32, NN / 16, 3), dim3(256), 0, stream,
                     text, kw2t, kw3v, Q, Spart);
  hipLaunchKernelGGL(combine_kernel, dim3(NN * MM / 1024), dim3(256), 0, stream,
                     Spart, text, out);
}

// Round 14
// 135.303 us; speedup vs baseline: 1.0283x; 1.0283x over previous
//
#include <hip/hip_runtime.h>

// Problem dims (hard-coded in reference)
#define DD   768
#define NN   512
#define MM   512

#define PRE_K 2.88539008177792681472f   // 2*log2(e)

typedef _Float16 h8 __attribute__((ext_vector_type(8)));  // 8 f16 (4 VGPRs)
typedef __attribute__((ext_vector_type(4))) float f32x4;  // MFMA C/D

__device__ __forceinline__ float fexp(float x) { return __builtin_amdgcn_exp2f(x); }
__device__ __forceinline__ float frcp(float x) { return __builtin_amdgcn_rcpf(x); }
// tanh(x) = 1 - 2/(1 + e^{2x}); saturates correctly via exp2->inf/0 + rcp.
__device__ __forceinline__ float fast_tanh(float x) {
  return 1.0f - 2.0f * frcp(fexp(PRE_K * x) + 1.0f);
}
// R13 lesson: Schraudolph fast-exp2 REGRESSED (45.0 -> 47.4, VALUBusy 69->79%):
// the ALU replacement issues MORE full-rate slots than one quarter-rate v_exp.
// Keep the hardware transcendental.

// fp32 -> f16 hi/lo split (pair covers ~21 mantissa bits)
__device__ __forceinline__ void splitf(float x, ushort& h, ushort& l) {
  const _Float16 hh = (_Float16)x;
  const _Float16 ll = (_Float16)(x - (float)hh);
  h = __builtin_bit_cast(unsigned short, hh);
  l = __builtin_bit_cast(unsigned short, ll);
}

// ---- fused prep ------------------------------------------------------------
// blocks [0,1344): elementwise f16 hi/lo split of text/visual/W3
// blocks [1344,2496): transpose+split W1/W2 -> [j][k]
// blocks [2496,2752): T-init — out[n,m] = T[n] = sum_d text[n,d]
//   (main then atomicAdds -2*S into out; replaces the combine kernel)
__global__ __launch_bounds__(256) void prep_kernel(
    const float* __restrict__ text, const float* __restrict__ visual,
    const float* __restrict__ W1, const float* __restrict__ W2,
    const float* __restrict__ W3,
    ushort* __restrict__ th, ushort* __restrict__ tl,
    ushort* __restrict__ vh, ushort* __restrict__ vl,
    ushort* __restrict__ w3h, ushort* __restrict__ w3l,
    ushort* __restrict__ w1th, ushort* __restrict__ w1tl,
    ushort* __restrict__ w2th, ushort* __restrict__ w2tl,
    float* __restrict__ out)
{
  __shared__ float Lt[32][33];
  const int b = blockIdx.x;
  const int t = threadIdx.x;

  if (b < 1344) {
    const float* src; ushort *dh, *dl; size_t off;
    if (b < 384)      { src = text;   dh = th;  dl = tl;  off = (size_t)b * 1024; }
    else if (b < 768) { src = visual; dh = vh;  dl = vl;  off = (size_t)(b - 384) * 1024; }
    else              { src = W3;     dh = w3h; dl = w3l; off = (size_t)(b - 768) * 1024; }
    const size_t i = off + (size_t)t * 4;
    const float4 v = *(const float4*)&src[i];
    ushort4 h, l;
    splitf(v.x, h.x, l.x); splitf(v.y, h.y, l.y);
    splitf(v.z, h.z, l.z); splitf(v.w, h.w, l.w);
    *(ushort4*)&dh[i] = h;
    *(ushort4*)&dl[i] = l;
  } else if (b < 2496) {
    const int tt = b - 1344;
    const bool second = tt >= 576;
    const int tile = second ? tt - 576 : tt;
    const float* W = second ? W2 : W1;
    ushort* oh = second ? w2th : w1th;
    ushort* ol = second ? w2tl : w1tl;
    const int k0 = (tile / 24) * 32, j0 = (tile % 24) * 32;
    {
      const int k = t >> 3, j4 = (t & 7) * 4;
      const float4 v = *(const float4*)&W[(size_t)(k0 + k) * DD + j0 + j4];
      Lt[j4 + 0][k] = v.x; Lt[j4 + 1][k] = v.y;
      Lt[j4 + 2][k] = v.z; Lt[j4 + 3][k] = v.w;
    }
    __syncthreads();
    {
      const int j = t >> 3, k4 = (t & 7) * 4;
      ushort4 h, l;
      splitf(Lt[j][k4 + 0], h.x, l.x); splitf(Lt[j][k4 + 1], h.y, l.y);
      splitf(Lt[j][k4 + 2], h.z, l.z); splitf(Lt[j][k4 + 3], h.w, l.w);
      *(ushort4*)&oh[(size_t)(j0 + j) * DD + k0 + k4] = h;
      *(ushort4*)&ol[(size_t)(j0 + j) * DD + k0 + k4] = l;
    }
  } else {
    // T-init: rows n0, n0+1; out[row][:] = T[row]
    float* red = (float*)Lt;          // 258 floats needed, 1056 available
    const int u = b - 2496;
    const int n0 = u * 2;
    const int half = t >> 7;
    const int lt = t & 127;

    const float* tr = text + (size_t)(n0 + half) * DD;
    float s = 0.f;
    #pragma unroll
    for (int i = 0; i < DD / 128; ++i) s += tr[lt + i * 128];
    red[t] = s;
    __syncthreads();
    #pragma unroll
    for (int st = 64; st > 0; st >>= 1) {
      if (lt < st) red[t] += red[t + st];
      __syncthreads();
    }
    const float Tn = red[half << 7];
    float4 o; o.x = Tn; o.y = Tn; o.z = Tn; o.w = Tn;
    *(float4*)&out[(size_t)(n0 + half) * MM + lt * 4] = o;
  }
}

// ---- staged-LDS MFMA GEMM core (proven R8/R9) ------------------------------
// ALO=false drops the a_lo*b_hi term (and a_lo staging entirely): used for the
// kw2t/kw3v GEMMs whose output only feeds the sigmoid argument.
#define BK   32
#define LROW 40   // padded LDS row stride (f16): 2-way banks, 16B-aligned

template <bool ALO>
__device__ __forceinline__ void gemm_core(
    const ushort* __restrict__ Ahg, const ushort* __restrict__ Alg,
    const ushort* __restrict__ Bhg, const ushort* __restrict__ Blg,
    int i0, int j0, int k0, int nsteps, f32x4* acc)
{
  __shared__ ushort As[2][2][64 * LROW];   // [buf][hi/lo][row*LROW+k]
  __shared__ ushort Bs[2][2][64 * LROW];

  const int tid  = threadIdx.x;
  const int row  = tid >> 2;            // 0..63 staging row
  const int ks8  = (tid & 3) * 8;       // 0,8,16,24 (f16)
  const size_t ga = (size_t)(i0 + row) * DD + k0 + ks8;
  const size_t gb = (size_t)(j0 + row) * DD + k0 + ks8;
  const int ldsw = row * LROW + ks8;

  const int lane = tid & 63, wave = tid >> 6;
  const int r15 = lane & 15, quad = lane >> 4;
  const int fa = (wave * 16 + r15) * LROW + quad * 8;   // A frag offset
  const int fb = r15 * LROW + quad * 8;                 // B frag base

  // prefetch step 0
  h8 pah = *(const h8*)(Ahg + ga);
  h8 pal; if (ALO) pal = *(const h8*)(Alg + ga);
  h8 pbh = *(const h8*)(Bhg + gb);
  h8 pbl = *(const h8*)(Blg + gb);

  int p = 0;
  *(h8*)&As[0][0][ldsw] = pah;
  if (ALO) *(h8*)&As[0][1][ldsw] = pal;
  *(h8*)&Bs[0][0][ldsw] = pbh; *(h8*)&Bs[0][1][ldsw] = pbl;
  __syncthreads();

  for (int s = 0; s < nsteps; ++s) {
    const bool more = (s + 1 < nsteps);
    if (more) {  // issue next chunk's globals; MFMA below hides latency
      pah = *(const h8*)(Ahg + ga + (s + 1) * BK);
      if (ALO) pal = *(const h8*)(Alg + ga + (s + 1) * BK);
      pbh = *(const h8*)(Bhg + gb + (s + 1) * BK);
      pbl = *(const h8*)(Blg + gb + (s + 1) * BK);
    }
    const h8 a_h = *(const h8*)&As[p][0][fa];
    h8 a_l; if (ALO) a_l = *(const h8*)&As[p][1][fa];
    h8 b_h[4], b_l[4];
    #pragma unroll
    for (int c = 0; c < 4; ++c) {
      b_h[c] = *(const h8*)&Bs[p][0][fb + c * 16 * LROW];
      b_l[c] = *(const h8*)&Bs[p][1][fb + c * 16 * LROW];
    }
    #pragma unroll
    for (int c = 0; c < 4; ++c)
      acc[c] = __builtin_amdgcn_mfma_f32_16x16x32_f16(a_h, b_h[c], acc[c], 0, 0, 0);
    #pragma unroll
    for (int c = 0; c < 4; ++c)
      acc[c] = __builtin_amdgcn_mfma_f32_16x16x32_f16(a_h, b_l[c], acc[c], 0, 0, 0);
    if (ALO) {
      #pragma unroll
      for (int c = 0; c < 4; ++c)
        acc[c] = __builtin_amdgcn_mfma_f32_16x16x32_f16(a_l, b_h[c], acc[c], 0, 0, 0);
    }
    if (more) {
      const int q = p ^ 1;
      *(h8*)&As[q][0][ldsw] = pah;
      if (ALO) *(h8*)&As[q][1][ldsw] = pal;
      *(h8*)&Bs[q][0][ldsw] = pbh; *(h8*)&Bs[q][1][ldsw] = pbl;
    }
    __syncthreads();
    p ^= 1;
  }
}

// z=0: A=text@W1 -> Ah/Al(f16)  z=1: kw2t=PRE_K*text@W2  z=2: kw3v=PRE_K*visual@W3^T
__global__ __launch_bounds__(256) void mfma1_kernel(
    const ushort* __restrict__ th, const ushort* __restrict__ tl,
    const ushort* __restrict__ vh, const ushort* __restrict__ vl,
    const ushort* __restrict__ w1th, const ushort* __restrict__ w1tl,
    const ushort* __restrict__ w2th, const ushort* __restrict__ w2tl,
    const ushort* __restrict__ w3h, const ushort* __restrict__ w3l,
    ushort* __restrict__ Ah, ushort* __restrict__ Al,
    float* __restrict__ kw2t, float* __restrict__ kw3v)
{
  const int z  = blockIdx.z;
  const int j0 = blockIdx.x * 64;
  const int i0 = blockIdx.y * 64;

  f32x4 acc[4];
  #pragma unroll
  for (int c = 0; c < 4; ++c) acc[c] = (f32x4){0.f, 0.f, 0.f, 0.f};

  if (z == 0)
    gemm_core<true >(th, tl, w1th, w1tl, i0, j0, 0, DD / BK, acc);
  else if (z == 1)
    gemm_core<false>(th, tl, w2th, w2tl, i0, j0, 0, DD / BK, acc);
  else
    gemm_core<false>(vh, vl, w3h,  w3l,  i0, j0, 0, DD / BK, acc);

  const int lane = threadIdx.x & 63, wave = threadIdx.x >> 6;
  const int r15 = lane & 15, quad = lane >> 4;
  // C/D layout: col=lane&15 (B row j), row=quad*4+reg (A row i)
  if (z == 0) {
    #pragma unroll
    for (int c = 0; c < 4; ++c)
      #pragma unroll
      for (int r = 0; r < 4; ++r) {
        const size_t o = (size_t)(i0 + wave * 16 + quad * 4 + r) * DD + j0 + c * 16 + r15;
        splitf(acc[c][r], Ah[o], Al[o]);
      }
  } else {
    float* Out = (z == 1) ? kw2t : kw3v;
    #pragma unroll
    for (int c = 0; c < 4; ++c)
      #pragma unroll
      for (int r = 0; r < 4; ++r)
        Out[(size_t)(i0 + wave * 16 + quad * 4 + r) * DD + j0 + c * 16 + r15] =
            acc[c][r] * PRE_K;
  }
}

// Q[z] = A @ visual^T over K quarter z.  grid (8,8,4) = 256 blocks.
__global__ __launch_bounds__(256) void mfma2_kernel(
    const ushort* __restrict__ Ah, const ushort* __restrict__ Al,
    const ushort* __restrict__ vh, const ushort* __restrict__ vl,
    float* __restrict__ Q)
{
  const int z  = blockIdx.z;
  const int j0 = blockIdx.x * 64;
  const int i0 = blockIdx.y * 64;

  f32x4 acc[4];
  #pragma unroll
  for (int c = 0; c < 4; ++c) acc[c] = (f32x4){0.f, 0.f, 0.f, 0.f};
  gemm_core<true>(Ah, Al, vh, vl, i0, j0, z * (DD / 4), (DD / 4) / BK, acc);

  const int lane = threadIdx.x & 63, wave = threadIdx.x >> 6;
  const int r15 = lane & 15, quad = lane >> 4;
  float* Out = Q + (size_t)z * NN * MM;
  #pragma unroll
  for (int c = 0; c < 4; ++c)
    #pragma unroll
    for (int r = 0; r < 4; ++r)
      Out[(size_t)(i0 + wave * 16 + quad * 4 + r) * MM + j0 + c * 16 + r15] = acc[c][r];
}

// ---- main fused kernel (R11-proven config: d-split x3, 1536 blocks, dbuf) --
// cval = tanh(sum_z Q[z][n,m]);
// out[n,m] -= 2 * sum_{d in third z} text[n,d]*rcp(1+exp2(kw2t[n,d]+kw3v[m,d]*cval))
// (out pre-initialized to T[n] by prep; atomics replace Spart+combine.
//  1.57M fp32 atomic adds ~ 6MB HBM flush — 12x below R2's pathological case.)
#define DCH    64
#define DRANGE 256
#define MLDW   68

__global__ __launch_bounds__(256) void main_kernel(
    const float* __restrict__ text, const float* __restrict__ kw2t,
    const float* __restrict__ kw3v, const float* __restrict__ Q,
    float* __restrict__ out)
{
  __shared__ float sbuf[2][64 * MLDW];   // 2 x 17408 B

  const int tid = threadIdx.x;
  const int nl = tid >> 4;
  const int ml = tid & 15;
  const int n0 = blockIdx.y * 16;
  const int m0 = blockIdx.x * 32;
  const int z  = blockIdx.z;
  const int n  = n0 + nl;
  const int mA = m0 + ml, mB = mA + 16;
  const int dbase = z * DRANGE;

  float cA = 0.f, cB = 0.f;
  #pragma unroll
  for (int zz = 0; zz < 4; ++zz) {
    const float* q = Q + (size_t)zz * NN * MM + (size_t)n * MM;
    cA += q[mA]; cB += q[mB];
  }
  cA = fast_tanh(cA); cB = fast_tanh(cB);

  float4 aA = {0.f, 0.f, 0.f, 0.f};
  float4 aB = {0.f, 0.f, 0.f, 0.f};

  const int srow = tid >> 4;              // staging row 0..15
  const int sc4  = (tid & 15) << 2;       // staging col 0..60
  const float* gt  = &text[(size_t)(n0 + srow) * DD + dbase + sc4];
  const float* g2  = &kw2t[(size_t)(n0 + srow) * DD + dbase + sc4];
  const float* g3a = &kw3v[(size_t)(m0 + srow) * DD + dbase + sc4];
  const float* g3b = &kw3v[(size_t)(m0 + 16 + srow) * DD + dbase + sc4];
  const int wt  = srow * MLDW + sc4;          // text rows
  const int w2  = (16 + srow) * MLDW + sc4;   // kw2t rows
  const int w3a = (32 + srow) * MLDW + sc4;   // kw3v rows (first 16)
  const int w3b = (48 + srow) * MLDW + sc4;   // kw3v rows (second 16)

  // prologue: stage chunk 0 into buffer 0
  float4 rt  = *(const float4*)gt;
  float4 r2  = *(const float4*)g2;
  float4 r3a = *(const float4*)g3a;
  float4 r3b = *(const float4*)g3b;
  int p = 0;
  *(float4*)&sbuf[0][wt]  = rt;
  *(float4*)&sbuf[0][w2]  = r2;
  *(float4*)&sbuf[0][w3a] = r3a;
  *(float4*)&sbuf[0][w3b] = r3b;
  __syncthreads();

  #pragma unroll
  for (int c = 0; c < DRANGE / DCH; ++c) {
    const bool more = (c + 1 < DRANGE / DCH);
    if (more) {  // prefetch next chunk; compute below hides latency
      rt  = *(const float4*)(gt  + (c + 1) * DCH);
      r2  = *(const float4*)(g2  + (c + 1) * DCH);
      r3a = *(const float4*)(g3a + (c + 1) * DCH);
      r3b = *(const float4*)(g3b + (c + 1) * DCH);
    }
    const float* bp = sbuf[p];
    #pragma unroll 4
    for (int j = 0; j < DCH; j += 4) {
      const float4 tv  = *(const float4*)&bp[nl * MLDW + j];
      const float4 w2v = *(const float4*)&bp[(16 + nl) * MLDW + j];
      const float4 w3A = *(const float4*)&bp[(32 + ml) * MLDW + j];
      const float4 w3B = *(const float4*)&bp[(48 + ml) * MLDW + j];
      aA.x = fmaf(tv.x, frcp(fexp(fmaf(w3A.x, cA, w2v.x)) + 1.0f), aA.x);
      aA.y = fmaf(tv.y, frcp(fexp(fmaf(w3A.y, cA, w2v.y)) + 1.0f), aA.y);
      aA.z = fmaf(tv.z, frcp(fexp(fmaf(w3A.z, cA, w2v.z)) + 1.0f), aA.z);
      aA.w = fmaf(tv.w, frcp(fexp(fmaf(w3A.w, cA, w2v.w)) + 1.0f), aA.w);
      aB.x = fmaf(tv.x, frcp(fexp(fmaf(w3B.x, cB, w2v.x)) + 1.0f), aB.x);
      aB.y = fmaf(tv.y, frcp(fexp(fmaf(w3B.y, cB, w2v.y)) + 1.0f), aB.y);
      aB.z = fmaf(tv.z, frcp(fexp(fmaf(w3B.z, cB, w2v.z)) + 1.0f), aB.z);
      aB.w = fmaf(tv.w, frcp(fexp(fmaf(w3B.w, cB, w2v.w)) + 1.0f), aB.w);
    }
    if (more) {
      const int q = p ^ 1;
      *(float4*)&sbuf[q][wt]  = rt;
      *(float4*)&sbuf[q][w2]  = r2;
      *(float4*)&sbuf[q][w3a] = r3a;
      *(float4*)&sbuf[q][w3b] = r3b;
    }
    __syncthreads();   // single barrier per chunk
    p ^= 1;
  }

  float* op = out + (size_t)n * MM;
  unsafeAtomicAdd(&op[mA], -2.0f * ((aA.x + aA.y) + (aA.z + aA.w)));
  unsafeAtomicAdd(&op[mB], -2.0f * ((aB.x + aB.y) + (aB.z + aB.w)));
}

// ---- launcher --------------------------------------------------------------
extern "C" void kernel_launch(void* const* d_in, const int* in_sizes, int n_in,
                              void* d_out, int out_size, void* d_ws, size_t ws_size,
                              hipStream_t stream) {
  const float* text   = (const float*)d_in[0];
  const float* visual = (const float*)d_in[1];
  const float* W1     = (const float*)d_in[2];
  const float* W2     = (const float*)d_in[3];
  const float* W3     = (const float*)d_in[4];
  float* out = (float*)d_out;

  // Workspace byte layout (peak 14.25 MB, proven available):
  //   th/tl/vh/vl : f16 hi/lo of text, visual     (4 x 768 KB)
  //   w1t/w2t h,l : f16 hi/lo of W1^T,W2^T [j][k] (4 x 1.125 MB)
  //   w3 h/l      : f16 hi/lo of W3 [j][k]        (2 x 1.125 MB)
  //   Ah/Al       : f16 hi/lo of A                (2 x 768 KB)
  //   kw2t/kw3v   : fp32                          (2 x 1.5 MB)
  // Overlay (stream-serial; sources dead before overwrite):
  //   Q (4 MB) -> w1th..w2tl  (dead after mfma1; mfma2 writes Q)
  char* base = (char*)d_ws;
  ushort* th   = (ushort*)(base);
  ushort* tl   = (ushort*)(base + 786432);
  ushort* vh   = (ushort*)(base + 1572864);
  ushort* vl   = (ushort*)(base + 2359296);
  ushort* w1th = (ushort*)(base + 3145728);
  ushort* w1tl = (ushort*)(base + 4325376);
  ushort* w2th = (ushort*)(base + 5505024);
  ushort* w2tl = (ushort*)(base + 6684672);
  ushort* w3h  = (ushort*)(base + 7864320);
  ushort* w3l  = (ushort*)(base + 9043968);
  ushort* Ah   = (ushort*)(base + 10223616);
  ushort* Al   = (ushort*)(base + 11010048);
  float*  kw2t = (float*) (base + 11796480);
  float*  kw3v = (float*) (base + 13369344);
  float*  Q    = (float*) (base + 3145728);   // 4 MB over w1t/w2t

  hipLaunchKernelGGL(prep_kernel, dim3(2752), dim3(256), 0, stream,
                     text, visual, W1, W2, W3,
                     th, tl, vh, vl, w3h, w3l, w1th, w1tl, w2th, w2tl, out);
  hipLaunchKernelGGL(mfma1_kernel, dim3(DD / 64, NN / 64, 3), dim3(256), 0, stream,
                     th, tl, vh, vl, w1th, w1tl, w2th, w2tl, w3h, w3l,
                     Ah, Al, kw2t, kw3v);
  hipLaunchKernelGGL(mfma2_kernel, dim3(MM / 64, NN / 64, 4), dim3(256), 0, stream,
                     Ah, Al, vh, vl, Q);
  hipLaunchKernelGGL(main_kernel, dim3(MM / 32, NN / 16, 3), dim3(256), 0, stream,
                     text, kw2t, kw3v, Q, out);
}